// Round 11
// baseline (5080.943 us; speedup 1.0000x reference)
//
#include <hip/hip_runtime.h>
#include <stdint.h>

#define B_ 64
#define T_ 512
#define I_ 256
#define H_ 512
#define NTHR_ 512
#define D_ 8   // ring depth in CYC fallback mode

typedef __attribute__((ext_vector_type(8))) short short8;
typedef __attribute__((ext_vector_type(4))) float float4v;
typedef __attribute__((ext_vector_type(4))) unsigned int uint4v;
typedef __attribute__((ext_vector_type(2))) unsigned int uint2v;

static_assert(sizeof(short8) == 16, "");

#define TILE_B 2048                       // per (bg,ktile): 1KB hi + 1KB lo frags
#define SLOT_B ((size_t)4 * 16 * TILE_B)  // 128 KB per slot

// ---- bf16 helpers (round-to-nearest-even) ----
__device__ __forceinline__ unsigned short f2bf(float x) {
  union { float f; uint32_t u; } v; v.f = x;
  uint32_t r = v.u + 0x7FFFu + ((v.u >> 16) & 1u);
  return (unsigned short)(r >> 16);
}
__device__ __forceinline__ float bf2f(unsigned short h) {
  union { uint32_t u; float f; } v; v.u = ((uint32_t)h) << 16; return v.f;
}
__device__ __forceinline__ void splitHL(float x, unsigned short& hi, unsigned short& lo) {
  hi = f2bf(x);
  lo = f2bf(x - bf2f(hi));   // x - hi is exact in fp32
}

// byte offset of a lane's hi-frag; lo-frag at +1024 (same tile)
__device__ __forceinline__ size_t rbyte(int slot, int bg, int ht, int lane) {
  return ((size_t)slot * 64 + bg * 16 + ht) * TILE_B + (size_t)lane * 16;
}

#define MFMA16(A, Bv, C) __builtin_amdgcn_mfma_f32_16x16x32_bf16(A, Bv, C, 0, 0, 0)

// counted wait on our asm-issued vmem + scheduling fence (rule #18)
#define WAITV(n) do { \
    asm volatile("s_waitcnt vmcnt(" #n ")" ::: "memory"); \
    __builtin_amdgcn_sched_barrier(0); \
  } while (0)
#define SB() __builtin_amdgcn_sched_barrier(0)

// One LSTM layer, persistent. 8 waves/block: (bg 0..3) x (kh 0..1), split-K.
// Block 'a' owns h-cols [4a,4a+4) -> 16 gate cols. K: [0,K1)=inp, [K1,K1+512)=h.
// MFMA frags: k(q,j)=4q+(j&3)+16*(j>>2); A-row=lane&15, B-col=lane&15,
// C/D col=lane&15 row=4*(lane>>4)+i (m89-verified).
//
// T-loop has ZERO __syncthreads. Intra-block sync is pairwise LDS handshakes:
//   red_ready[bg]: kh1 wrote its split-K partial (LDS red)  -> kh0 may read
//   h_done[bg]:    kh0 drained h stores + flag               -> pair may read own cols
// Cross-block sync: per-wave flag words prog[layer][bg*128+a] (stores, no RMW);
// each wave polls ONLY its bg's 128-word group collectively (dwordx2/lane +
// __all), own word skipped (covered by h_done).
// FULL: write-once rings (T+1 slots, slot s = h[s-1], slot0 zeroed), plain
// cached ring reads (flag-gated first touch -> always fresh).
// CYC fallback: D=8 circular ring, sc0 sc1 bypass reads, backpressure poll.
template <int LAYER, bool FULL>
__device__ void run_layer(
    int a,
    const float* __restrict__ x,
    const float* __restrict__ Wxp, const float* __restrict__ bxp,
    const float* __restrict__ Whp,
    uint32_t* prog0, uint32_t* prog1,
    uint8_t* r0, uint8_t* r1,
    float* h1f,
    unsigned short* WshHi, unsigned short* WshLo, float* red,
    volatile int* red_ready, volatile int* h_done)
{
  constexpr int K1 = LAYER ? H_ : I_;
  constexpr int NT = (K1 + H_) / 32;   // 24 (L0) or 32 (L1) K-tiles
  const int tid = threadIdx.x;
  const int lane = tid & 63;
  const int wid = tid >> 6;     // 0..7
  const int bg = wid & 3;       // batch group (16 batches)
  const int kh = wid >> 2;      // K-half (tile parity)
  const int qq = lane >> 4;
  const int cc = lane & 15;
  const int brow = bg * 16 + cc;

  if (tid < 4) { red_ready[tid] = 0; h_done[tid] = 0; }
  // ---- stage weights: hi AND lo to LDS (one pass) ----
  for (int idx = tid; idx < NT * 512; idx += NTHR_) {
    int tile = idx >> 9, r = idx & 511, ln = r >> 3, j = r & 7;
    int k = tile * 32 + 4 * (ln >> 4) + (j & 3) + 16 * (j >> 2);
    int n = 4 * a + (ln & 3);
    int g = (ln & 15) >> 2;
    float wvv = (k < K1) ? Wxp[((size_t)g * K1 + k) * H_ + n]
                         : Whp[((size_t)g * H_ + (k - K1)) * H_ + n];
    unsigned short hi, lo; splitHL(wvv, hi, lo);
    WshHi[idx] = hi; WshLo[idx] = lo;
  }
  __syncthreads();   // last block barrier; T-loop below is barrier-free

  const float biasv = bxp[(size_t)(cc >> 2) * H_ + 4 * a + (cc & 3)];
  float cst[4] = {0.f, 0.f, 0.f, 0.f};

  uint32_t* myflag = (LAYER ? prog1 : prog0) + bg * 128 + a;
  const uint32_t* g0 = prog0 + bg * 128;
  const uint32_t* g1 = prog1 + bg * 128;
  const bool s0own = (2 * lane == a), s1own = (2 * lane + 1 == a);

  // wave-collective poll of one 128-word flag group (4 cache lines)
  auto pollg = [&](const uint32_t* grp, int tgt, bool skipOwn) {
    if (tgt <= 0) return;
    const unsigned long long* p = (const unsigned long long*)grp + lane;
    int it = 0;
    while (true) {
      unsigned long long v = __hip_atomic_load(p, __ATOMIC_RELAXED,
                                               __HIP_MEMORY_SCOPE_AGENT);
      bool ok = ((skipOwn && s0own) || (int)(uint32_t)v >= tgt) &&
                ((skipOwn && s1own) || (int)(uint32_t)(v >> 32) >= tgt);
      if (__all((int)ok)) return;
      __builtin_amdgcn_s_sleep(1);
      if (++it > 2000000) return;   // degrade to wrong answer, never hang
    }
  };

  for (int t = 0; t < T_; ++t) {
    const int slotP = FULL ? t       : (t & (D_ - 1));        // h[t-1]
    const int slotC = FULL ? (t + 1) : ((t + 1) & (D_ - 1));  // h[t]
    // BIAS ONLY IN kh0's accumulator: split-K reduce sums both halves
    // (round-10 bug: unconditional biasv -> bias double-counted).
    const float bv = (kh == 0) ? biasv : 0.f;
    float4v accA = {bv, bv, bv, bv};              // hi*Whi (+bias in kh0)
    float4v accB = {0.f, 0.f, 0.f, 0.f};          // lo*Whi
    float4v accC = {0.f, 0.f, 0.f, 0.f};          // hi*Wlo

    short8 hb[8], lb[8], hb2[8], lb2[8];

    // own-pair h visibility (LDS spin, ~ns; covers own-block ring cols)
    { int it = 0; while (h_done[bg] < t) { if (++it > 100000000) break; } }
    SB();

    auto issue_ring = [&](short8* hd, short8* ld, int tile) {
      const uint8_t* p;
      if (!LAYER)         p = r0 + rbyte(slotP, bg, tile - 8, lane);
      else if (tile < 16) p = r0 + rbyte(slotC, bg, tile, lane);
      else                p = r1 + rbyte(slotP, bg, tile - 16, lane);
      if constexpr (FULL) {
        asm volatile("global_load_dwordx4 %0, %2, off\n\t"
                     "global_load_dwordx4 %1, %2, off offset:1024"
                     : "=&v"(*hd), "=&v"(*ld) : "v"(p) : "memory");
      } else {
        asm volatile("global_load_dwordx4 %0, %2, off sc0 sc1\n\t"
                     "global_load_dwordx4 %1, %2, off offset:1024 sc0 sc1"
                     : "=&v"(*hd), "=&v"(*ld) : "v"(p) : "memory");
      }
    };
    auto proc_tile = [&](short8 h, short8 l, int tile) {
      short8 bhi = *(const short8*)(WshHi + tile * 512 + lane * 8);
      short8 blo = *(const short8*)(WshLo + tile * 512 + lane * 8);
      accA = MFMA16(h, bhi, accA);
      accB = MFMA16(l, bhi, accB);
      accC = MFMA16(h, blo, accC);
    };

    if constexpr (!LAYER) {
      uint4v xw0[4], xw1[4];
      #pragma unroll
      for (int u = 0; u < 4; ++u) {        // x tiles 2u+kh (read-only: cached)
        const float* xp = x + ((size_t)brow * T_ + t) * I_ + (2 * u + kh) * 32 + 4 * qq;
        asm volatile("global_load_dwordx4 %0, %2, off\n\t"
                     "global_load_dwordx4 %1, %2, off offset:64"
                     : "=&v"(xw0[u]), "=&v"(xw1[u]) : "v"(xp) : "memory");
      }
      pollg(g0, t, true);                  // x lands under the poll
      if constexpr (!FULL) pollg(g1, t - (D_ - 1), false);   // CYC backpressure
      SB();
      #pragma unroll
      for (int u = 0; u < 8; ++u) issue_ring(&hb[u], &lb[u], 2 * (u + 4) + kh);
      WAITV(16);                           // x retired (<=16 ring outstanding)
      #pragma unroll
      for (int u = 0; u < 4; ++u) {        // convert+MFMA x under ring flight
        short8 ahi, alo;
        #pragma unroll
        for (int j = 0; j < 4; ++j) {
          unsigned short hh, ll;
          splitHL(__uint_as_float(xw0[u][j]), hh, ll); ahi[j] = (short)hh; alo[j] = (short)ll;
          splitHL(__uint_as_float(xw1[u][j]), hh, ll); ahi[j + 4] = (short)hh; alo[j + 4] = (short)ll;
        }
        proc_tile(ahi, alo, 2 * u + kh);
      }
      WAITV(8);
      #pragma unroll
      for (int u = 0; u < 4; ++u) proc_tile(hb[u], lb[u], 2 * (u + 4) + kh);
      WAITV(0);
      #pragma unroll
      for (int u = 4; u < 8; ++u) proc_tile(hb[u], lb[u], 2 * (u + 4) + kh);
    } else {
      pollg(g0, t + 1, false);             // h0[t]: L0 runs ahead -> ~instant
      SB();
      #pragma unroll
      for (int u = 0; u < 8; ++u) issue_ring(&hb[u], &lb[u], 2 * u + kh);   // ring0
      pollg(g1, t, true);                  // the real wait; ring0 fetch overlaps
      SB();
      #pragma unroll
      for (int u = 0; u < 8; ++u) issue_ring(&hb2[u], &lb2[u], 16 + 2 * u + kh); // ring1
      WAITV(16);                           // ring0 done (fetched under poll)
      #pragma unroll
      for (int u = 0; u < 8; ++u) proc_tile(hb[u], lb[u], 2 * u + kh);
      WAITV(0);
      #pragma unroll
      for (int u = 0; u < 8; ++u) proc_tile(hb2[u], lb2[u], 16 + 2 * u + kh);
    }

    float4v acc = accA + accB + accC;

    // ---- split-K reduce via pairwise LDS handshake (no block barrier) ----
    if (kh == 1) {
      *(float4v*)(red + ((bg << 6) + lane) * 4) = acc;
      asm volatile("s_waitcnt lgkmcnt(0)" ::: "memory");
      red_ready[bg] = t + 1;
      // kh1 proceeds straight to t+1; h_done spin there orders red reuse
    } else {
      { int it = 0; while (red_ready[bg] < t + 1) { if (++it > 100000000) break; } }
      SB();
      acc += *(const float4v*)(red + ((bg << 6) + lane) * 4);

      // activations: cols 0-11 sigmoid (i,f,o), 12-15 tanh (g)
      const bool isg = cc >= 12;
      float av[4];
      #pragma unroll
      for (int i = 0; i < 4; ++i) {
        float xg = acc[i];
        float arg = isg ? xg + xg : xg;
        float e = __expf(-fabsf(arg));
        float s = (arg >= 0.f) ? 1.f / (1.f + e) : e / (1.f + e);
        av[i] = isg ? (s + s - 1.f) : s;   // tanh(x) = 2*sigmoid(2x)-1
      }
      float hn[4];
      #pragma unroll
      for (int i = 0; i < 4; ++i) {
        float fv = __shfl_xor(av[i], 4);
        float ov = __shfl_xor(av[i], 8);
        float gv = __shfl_xor(av[i], 12);
        float cn = fv * cst[i] + av[i] * gv;
        cst[i] = cn;
        float e2 = __expf(-2.f * fabsf(cn));
        float th = (1.f - e2) / (1.f + e2);
        hn[i] = ov * ((cn >= 0.f) ? th : -th);
      }
      // in-wave transpose: lane (qq,cc<4) gathers row 4qq+cc, cols 4a+0..3
      float v0[4], v1[4], v2[4], v3[4];
      #pragma unroll
      for (int d = 0; d < 4; ++d) {
        int src = (lane & 0x30) | d;
        v0[d] = __shfl(hn[0], src);
        v1[d] = __shfl(hn[1], src);
        v2[d] = __shfl(hn[2], src);
        v3[d] = __shfl(hn[3], src);
      }
      if (cc < 4) {
        unsigned short hh[4], ll[4]; float4v hf;
        #pragma unroll
        for (int d = 0; d < 4; ++d) {
          float hv = (cc == 0) ? v0[d] : (cc == 1) ? v1[d] : (cc == 2) ? v2[d] : v3[d];
          hf[d] = hv;
          splitHL(hv, hh[d], ll[d]);
        }
        uint2v hi2, lo2;
        hi2[0] = (uint32_t)hh[0] | ((uint32_t)hh[1] << 16);
        hi2[1] = (uint32_t)hh[2] | ((uint32_t)hh[3] << 16);
        lo2[0] = (uint32_t)ll[0] | ((uint32_t)ll[1] << 16);
        lo2[1] = (uint32_t)ll[2] | ((uint32_t)ll[3] << 16);
        // frag store: lane' = 16*(a&3)+(4qq+cc), shorts j0..j0+3, j0=4*((a>>2)&1)
        uint8_t* dst = (LAYER ? r1 : r0)
                     + rbyte(slotC, bg, a >> 3, 16 * (a & 3) + 4 * qq + cc)
                     + 8 * ((a >> 2) & 1);
        asm volatile("global_store_dwordx2 %0, %1, off sc0 sc1\n\t"
                     "global_store_dwordx2 %0, %2, off offset:1024 sc0 sc1"
                     :: "v"(dst), "v"(hi2), "v"(lo2) : "memory");
        if (LAYER && t == T_ - 1) {
          float4v* hp = (float4v*)(h1f + (size_t)(bg * 16 + 4 * qq + cc) * H_ + 4 * a);
          asm volatile("global_store_dwordx4 %0, %1, off sc0 sc1"
                       :: "v"(hp), "v"(hf) : "memory");
        }
      }
      // drain this wave's stores (acked at MALL) -> publish flag + LDS h_done
      asm volatile("s_waitcnt vmcnt(0)" ::: "memory");
      if (lane == 0)
        __hip_atomic_store(myflag, (uint32_t)(t + 1),
                           __ATOMIC_RELAXED, __HIP_MEMORY_SCOPE_AGENT);
      h_done[bg] = t + 1;
    }
  }
}

template <bool FULL>
__global__ __launch_bounds__(NTHR_, 2) void lstm_persist(
    const float* __restrict__ x,
    const float* __restrict__ Wx0, const float* __restrict__ bx0, const float* __restrict__ Wh0,
    const float* __restrict__ Wx1, const float* __restrict__ bx1, const float* __restrict__ Wh1,
    uint32_t* prog0, uint32_t* prog1,
    uint8_t* ring0, uint8_t* ring1,
    float* h1f)
{
  __shared__ unsigned short WshHi[16384];  // 32 KB
  __shared__ unsigned short WshLo[16384];  // 32 KB
  __shared__ float red[1024];              // 4 KB split-K exchange
  __shared__ volatile int red_ready[4];
  __shared__ volatile int h_done[4];
  if (blockIdx.x < 128)
    run_layer<0, FULL>(blockIdx.x, x, Wx0, bx0, Wh0, prog0, prog1, ring0, ring1,
                       h1f, WshHi, WshLo, red, red_ready, h_done);
  else
    run_layer<1, FULL>(blockIdx.x - 128, x, Wx1, bx1, Wh1, prog0, prog1, ring0, ring1,
                       h1f, WshHi, WshLo, red, red_ready, h_done);
}

__global__ void fc_out(const float* __restrict__ h1f, const float* __restrict__ Wfc,
                       const float* __restrict__ bfc, float* __restrict__ out)
{
  int tid = threadIdx.x;
  int b = tid >> 3, p = tid & 7;
  const float* hp = h1f + (size_t)b * H_ + p * 64;
  const float* wp = Wfc + p * 64;
  float4v hv[16];
  #pragma unroll
  for (int q = 0; q < 16; ++q)
    asm volatile("global_load_dwordx4 %0, %1, off sc0 sc1"
                 : "=&v"(hv[q]) : "v"(hp + 4 * q) : "memory");
  asm volatile("s_waitcnt vmcnt(0)" ::: "memory");
  float s = 0.f;
  #pragma unroll
  for (int q = 0; q < 16; ++q) {
    float4v wv = *(const float4v*)(wp + 4 * q);
    s += hv[q][0] * wv[0] + hv[q][1] * wv[1] + hv[q][2] * wv[2] + hv[q][3] * wv[3];
  }
  s += __shfl_xor(s, 1);
  s += __shfl_xor(s, 2);
  s += __shfl_xor(s, 4);
  if (p == 0) out[b] = s + bfc[0];
}

extern "C" void kernel_launch(void* const* d_in, const int* in_sizes, int n_in,
                              void* d_out, int out_size, void* d_ws, size_t ws_size,
                              hipStream_t stream)
{
  const float* x   = (const float*)d_in[0];
  const float* Wx0 = (const float*)d_in[1];
  const float* bx0 = (const float*)d_in[2];
  const float* Wh0 = (const float*)d_in[3];
  const float* Wx1 = (const float*)d_in[4];
  const float* bx1 = (const float*)d_in[5];
  const float* Wh1 = (const float*)d_in[6];
  const float* Wfc = (const float*)d_in[7];
  const float* bfc = (const float*)d_in[8];

  uint8_t* ws = (uint8_t*)d_ws;
  const size_t RINGB_FULL = (size_t)(T_ + 1) * SLOT_B;   // 65.7 MB per ring
  const size_t RINGB_CYC  = (size_t)D_ * SLOT_B;         // 1 MB per ring
  const size_t NEED_FULL  = 4096 + 2 * RINGB_FULL + (size_t)B_ * H_ * 4;

  // flags: prog[layer][bg*128+a] -> 2 x 512 u32 = 4 KB
  uint32_t* prog0 = (uint32_t*)ws;
  uint32_t* prog1 = (uint32_t*)(ws + 2048);

  if (ws_size >= NEED_FULL) {
    uint8_t* ring0 = ws + 4096;
    uint8_t* ring1 = ws + 4096 + RINGB_FULL;
    float* h1f = (float*)(ws + 4096 + 2 * RINGB_FULL);
    (void)hipMemsetAsync(ws, 0, 4096 + SLOT_B, stream);   // flags + ring0 slot0
    (void)hipMemsetAsync(ring1, 0, SLOT_B, stream);       // ring1 slot0
    hipLaunchKernelGGL(lstm_persist<true>, dim3(256), dim3(NTHR_), 0, stream,
                       x, Wx0, bx0, Wh0, Wx1, bx1, Wh1,
                       prog0, prog1, ring0, ring1, h1f);
    hipLaunchKernelGGL(fc_out, dim3(1), dim3(512), 0, stream,
                       h1f, Wfc, bfc, (float*)d_out);
  } else {
    uint8_t* ring0 = ws + 4096;
    uint8_t* ring1 = ws + 4096 + RINGB_CYC;
    float* h1f = (float*)(ws + 4096 + 2 * RINGB_CYC);
    (void)hipMemsetAsync(ws, 0, 4096 + 2 * RINGB_CYC, stream);
    hipLaunchKernelGGL(lstm_persist<false>, dim3(256), dim3(NTHR_), 0, stream,
                       x, Wx0, bx0, Wh0, Wx1, bx1, Wh1,
                       prog0, prog1, ring0, ring1, h1f);
    hipLaunchKernelGGL(fc_out, dim3(1), dim3(512), 0, stream,
                       h1f, Wfc, bfc, (float*)d_out);
  }
}

// Round 12
// 3126.350 us; speedup vs baseline: 1.6252x; 1.6252x over previous
//
#include <hip/hip_runtime.h>
#include <stdint.h>

#define B_ 64
#define T_ 512
#define I_ 256
#define H_ 512
#define NTHR_ 512
#define D_ 8   // ring depth in CYC fallback mode

typedef __attribute__((ext_vector_type(8))) short short8;
typedef __attribute__((ext_vector_type(4))) float float4v;
typedef __attribute__((ext_vector_type(4))) unsigned int uint4v;
typedef __attribute__((ext_vector_type(2))) unsigned int uint2v;

static_assert(sizeof(short8) == 16, "");

#define TILE_B 2048                       // per (bg,ktile): 1KB hi + 1KB lo frags
#define SLOT_B ((size_t)4 * 16 * TILE_B)  // 128 KB per slot

// ---- bf16 helpers (round-to-nearest-even) ----
__device__ __forceinline__ unsigned short f2bf(float x) {
  union { float f; uint32_t u; } v; v.f = x;
  uint32_t r = v.u + 0x7FFFu + ((v.u >> 16) & 1u);
  return (unsigned short)(r >> 16);
}
__device__ __forceinline__ float bf2f(unsigned short h) {
  union { uint32_t u; float f; } v; v.u = ((uint32_t)h) << 16; return v.f;
}
__device__ __forceinline__ void splitHL(float x, unsigned short& hi, unsigned short& lo) {
  hi = f2bf(x);
  lo = f2bf(x - bf2f(hi));   // x - hi is exact in fp32
}

// byte offset of a lane's hi-frag; lo-frag at +1024 (same tile)
__device__ __forceinline__ size_t rbyte(int slot, int bg, int ht, int lane) {
  return ((size_t)slot * 64 + bg * 16 + ht) * TILE_B + (size_t)lane * 16;
}

// per-thread spin on one progress word (bypass load)
__device__ __forceinline__ void wait_ge(const uint32_t* p, int tgt) {
  if (tgt <= 0) return;
  int it = 0;
  while ((int)__hip_atomic_load(p, __ATOMIC_RELAXED, __HIP_MEMORY_SCOPE_AGENT) < tgt) {
    __builtin_amdgcn_s_sleep(1);
    if (++it > 2000000) break;   // safety: degrade to wrong answer, never hang
  }
}

#define MFMA16(A, Bv, C) __builtin_amdgcn_mfma_f32_16x16x32_bf16(A, Bv, C, 0, 0, 0)

// counted wait on our asm-issued vmem + scheduling fence (rule #18)
#define WAITV(n) do { \
    asm volatile("s_waitcnt vmcnt(" #n ")" ::: "memory"); \
    __builtin_amdgcn_sched_barrier(0); \
  } while (0)
#define SB() __builtin_amdgcn_sched_barrier(0)

// One LSTM layer, persistent. 8 waves/block: (bg 0..3) x (kh 0..1), split-K.
// Block 'a' owns h-cols [4a,4a+4) -> 16 gate cols. K: [0,K1)=inp, [K1,K1+512)=h.
// MFMA frags: k(q,j)=4q+(j&3)+16*(j>>2); A-row=lane&15, B-col=lane&15,
// C/D col=lane&15 row=4*(lane>>4)+i (m89-verified).
//
// PROVEN round-8 structure (3.00 ms): 3 __syncthreads per step, W-lo in
// registers (wlo), per-thread-word flag polls with s_sleep, per-wave flag
// stores prog[layer][bg*128+a] after vmcnt(0) drain; own-block words skipped
// (ownw) -- intra-block ordering via the end-of-step barrier.
// ROUND-12 CHANGE (only one): L1's poll is SPLIT -- poll prog0 (h0[t], L0
// runs ahead -> ~instant), fetch+process the h0 half, THEN poll prog1
// (own-layer recurrence, the real wait). The h0 phase overlaps other blocks'
// epilogue+drain, shortening the recurrence self-loop.
// FULL: write-once rings (T+1 slots, slot s = h[s-1], slot0 zeroed), plain
// cached ring reads (flag-gated first touch -> always fresh).
// CYC fallback: D=8 circular ring, sc0 sc1 bypass reads, backpressure poll.
template <int LAYER, bool FULL>
__device__ void run_layer(
    int a,
    const float* __restrict__ x,
    const float* __restrict__ Wxp, const float* __restrict__ bxp,
    const float* __restrict__ Whp,
    uint32_t* prog0, uint32_t* prog1,
    uint8_t* r0, uint8_t* r1,
    float* h1f,
    unsigned short* Wsh, float* red)
{
  constexpr int K1 = LAYER ? H_ : I_;
  constexpr int NT = (K1 + H_) / 32;   // 24 (L0) or 32 (L1) K-tiles
  constexpr int NTT = NT / 2;          // 12 or 16 tiles per k-half wavegroup
  const int tid = threadIdx.x;
  const int lane = tid & 63;
  const int wid = tid >> 6;     // 0..7
  const int bg = wid & 3;       // batch group (16 batches)
  const int kh = wid >> 2;      // K-half (tile parity)
  const int qq = lane >> 4;
  const int cc = lane & 15;
  const int brow = bg * 16 + cc;

  // ---- stage weight slice: pass0 = LO (pulled to regs), pass1 = HI (stays in LDS) ----
  short8 wlo[NTT];
  for (int pass = 0; pass < 2; ++pass) {
    for (int idx = tid; idx < NT * 512; idx += NTHR_) {
      int tile = idx >> 9, r = idx & 511, ln = r >> 3, j = r & 7;
      int k = tile * 32 + 4 * (ln >> 4) + (j & 3) + 16 * (j >> 2);
      int n = 4 * a + (ln & 3);
      int g = (ln & 15) >> 2;
      float wvv = (k < K1) ? Wxp[((size_t)g * K1 + k) * H_ + n]
                           : Whp[((size_t)g * H_ + (k - K1)) * H_ + n];
      unsigned short hi, lo; splitHL(wvv, hi, lo);
      Wsh[idx] = pass ? hi : lo;
    }
    __syncthreads();
    if (pass == 0) {
      #pragma unroll
      for (int tt = 0; tt < NTT; ++tt) {
        int tile = 2 * tt + kh;
        wlo[tt] = *(const short8*)(Wsh + tile * 512 + lane * 8);
      }
      __syncthreads();   // all pulled before HI overwrites
    }
  }

  const float biasv = bxp[(size_t)(cc >> 2) * H_ + 4 * a + (cc & 3)];
  float cst[4] = {0.f, 0.f, 0.f, 0.f};

  uint32_t* myprog = LAYER ? prog1 : prog0;
  const bool ownw = FULL ? ((tid & 127) == a) : false;

  for (int t = 0; t < T_; ++t) {
    const int slotP = FULL ? t       : (t & (D_ - 1));        // h[t-1]
    const int slotC = FULL ? (t + 1) : ((t + 1) & (D_ - 1));  // h[t]
    const float bv = (kh == 0) ? biasv : 0.f;   // bias only in kh0 (split-K sums halves)
    float4v accA = {bv, bv, bv, bv};              // hi*Whi (+bias in kh0)
    float4v accB = {0.f, 0.f, 0.f, 0.f};          // lo*Whi
    float4v accC = {0.f, 0.f, 0.f, 0.f};          // hi*Wlo

    short8 hbuf[8], lbuf[8];

    auto issue_ring = [&](int tt) {
      const int tile = 2 * tt + kh;
      const uint8_t* p;
      if (!LAYER)         p = r0 + rbyte(slotP, bg, tile - 8, lane);
      else if (tile < 16) p = r0 + rbyte(slotC, bg, tile, lane);
      else                p = r1 + rbyte(slotP, bg, tile - 16, lane);
      if constexpr (FULL) {
        asm volatile("global_load_dwordx4 %0, %2, off\n\t"
                     "global_load_dwordx4 %1, %2, off offset:1024"
                     : "=&v"(hbuf[tt & 7]), "=&v"(lbuf[tt & 7]) : "v"(p) : "memory");
      } else {
        asm volatile("global_load_dwordx4 %0, %2, off sc0 sc1\n\t"
                     "global_load_dwordx4 %1, %2, off offset:1024 sc0 sc1"
                     : "=&v"(hbuf[tt & 7]), "=&v"(lbuf[tt & 7]) : "v"(p) : "memory");
      }
    };
    auto proc_ring = [&](int tt) {
      const int tile = 2 * tt + kh;
      short8 bhi = *(const short8*)(Wsh + tile * 512 + lane * 8);
      accA = MFMA16(hbuf[tt & 7], bhi, accA);
      accB = MFMA16(lbuf[tt & 7], bhi, accB);
      accC = MFMA16(hbuf[tt & 7], wlo[tt], accC);
    };

    if constexpr (!LAYER) {
      uint4v xw0[4], xw1[4];
      #pragma unroll
      for (int u = 0; u < 4; ++u) {        // x tiles 2u+kh (read-only: cached)
        const float* xp = x + ((size_t)brow * T_ + t) * I_ + (2 * u + kh) * 32 + 4 * qq;
        asm volatile("global_load_dwordx4 %0, %2, off\n\t"
                     "global_load_dwordx4 %1, %2, off offset:64"
                     : "=&v"(xw0[u]), "=&v"(xw1[u]) : "v"(xp) : "memory");
      }
      if constexpr (FULL) {
        if (!ownw) wait_ge(&prog0[tid], t);
      } else {
        if (tid < 128)      wait_ge(&prog0[tid], t);
        else if (tid < 256) wait_ge(&prog1[tid - 128], t - (D_ - 1));
      }
      __syncthreads();
      #pragma unroll
      for (int tt = 4; tt < 12; ++tt) issue_ring(tt);
      WAITV(16);                           // x retired (<=16 ring outstanding)
      #pragma unroll
      for (int u = 0; u < 4; ++u) {        // convert+MFMA x under ring flight
        short8 ahi, alo;
        #pragma unroll
        for (int j = 0; j < 4; ++j) {
          unsigned short hh, ll;
          splitHL(__uint_as_float(xw0[u][j]), hh, ll); ahi[j] = (short)hh; alo[j] = (short)ll;
          splitHL(__uint_as_float(xw1[u][j]), hh, ll); ahi[j + 4] = (short)hh; alo[j + 4] = (short)ll;
        }
        const int tile = 2 * u + kh;
        short8 bhi = *(const short8*)(Wsh + tile * 512 + lane * 8);
        accA = MFMA16(ahi, bhi, accA);
        accB = MFMA16(alo, bhi, accB);
        accC = MFMA16(ahi, wlo[u], accC);
      }
      WAITV(8);
      proc_ring(4); proc_ring(5); proc_ring(6); proc_ring(7);
      WAITV(0);
      proc_ring(8); proc_ring(9); proc_ring(10); proc_ring(11);
    } else {
      if constexpr (FULL) {
        // SPLIT POLL: h0 half first (L0 ahead -> ~instant), processed fully;
        // only then the own-layer wait -> ring0 phase off the self-loop.
        wait_ge(&prog0[tid], t + 1);
        __syncthreads();
        #pragma unroll
        for (int tt = 0; tt < 8; ++tt) issue_ring(tt);
        WAITV(8);
        proc_ring(0); proc_ring(1); proc_ring(2); proc_ring(3);
        WAITV(0);
        proc_ring(4); proc_ring(5); proc_ring(6); proc_ring(7);
        if (!ownw) wait_ge(&prog1[tid], t);
        __syncthreads();
        #pragma unroll
        for (int tt = 8; tt < 16; ++tt) issue_ring(tt);
        WAITV(8);
        proc_ring(8); proc_ring(9); proc_ring(10); proc_ring(11);
        WAITV(0);
        proc_ring(12); proc_ring(13); proc_ring(14); proc_ring(15);
      } else {
        if (tid < 128)      wait_ge(&prog0[tid], t + 1);
        else if (tid < 256) wait_ge(&prog1[tid - 128], t);
        __syncthreads();
        #pragma unroll
        for (int tt = 0; tt < 8; ++tt) issue_ring(tt);
        WAITV(8);
        proc_ring(0); proc_ring(1); proc_ring(2); proc_ring(3);
        issue_ring(8); issue_ring(9); issue_ring(10); issue_ring(11);
        WAITV(8);
        proc_ring(4); proc_ring(5); proc_ring(6); proc_ring(7);
        issue_ring(12); issue_ring(13); issue_ring(14); issue_ring(15);
        WAITV(8);
        proc_ring(8); proc_ring(9); proc_ring(10); proc_ring(11);
        WAITV(0);
        proc_ring(12); proc_ring(13); proc_ring(14); proc_ring(15);
      }
    }

    float4v acc = accA + accB + accC;

    // ---- split-K reduction through LDS ----
    if (kh == 1) *(float4v*)(red + ((bg << 6) + lane) * 4) = acc;
    __syncthreads();
    if (kh == 0) {
      acc += *(const float4v*)(red + ((bg << 6) + lane) * 4);

      // activations: cols 0-11 sigmoid (i,f,o), 12-15 tanh (g)
      const bool isg = cc >= 12;
      float av[4];
      #pragma unroll
      for (int i = 0; i < 4; ++i) {
        float xg = acc[i];
        float arg = isg ? xg + xg : xg;
        float e = __expf(-fabsf(arg));
        float s = (arg >= 0.f) ? 1.f / (1.f + e) : e / (1.f + e);
        av[i] = isg ? (s + s - 1.f) : s;   // tanh(x) = 2*sigmoid(2x)-1
      }
      float hn[4];
      #pragma unroll
      for (int i = 0; i < 4; ++i) {
        float fv = __shfl_xor(av[i], 4);
        float ov = __shfl_xor(av[i], 8);
        float gv = __shfl_xor(av[i], 12);
        float cn = fv * cst[i] + av[i] * gv;
        cst[i] = cn;
        float e2 = __expf(-2.f * fabsf(cn));
        float th = (1.f - e2) / (1.f + e2);
        hn[i] = ov * ((cn >= 0.f) ? th : -th);
      }
      // in-wave transpose: lane (qq,cc<4) gathers row 4qq+cc, cols 4a+0..3
      float v0[4], v1[4], v2[4], v3[4];
      #pragma unroll
      for (int d = 0; d < 4; ++d) {
        int src = (lane & 0x30) | d;
        v0[d] = __shfl(hn[0], src);
        v1[d] = __shfl(hn[1], src);
        v2[d] = __shfl(hn[2], src);
        v3[d] = __shfl(hn[3], src);
      }
      if (cc < 4) {
        unsigned short hh[4], ll[4]; float4v hf;
        #pragma unroll
        for (int d = 0; d < 4; ++d) {
          float hv = (cc == 0) ? v0[d] : (cc == 1) ? v1[d] : (cc == 2) ? v2[d] : v3[d];
          hf[d] = hv;
          splitHL(hv, hh[d], ll[d]);
        }
        uint2v hi2, lo2;
        hi2[0] = (uint32_t)hh[0] | ((uint32_t)hh[1] << 16);
        hi2[1] = (uint32_t)hh[2] | ((uint32_t)hh[3] << 16);
        lo2[0] = (uint32_t)ll[0] | ((uint32_t)ll[1] << 16);
        lo2[1] = (uint32_t)ll[2] | ((uint32_t)ll[3] << 16);
        // frag store: lane' = 16*(a&3)+(4qq+cc), shorts j0..j0+3, j0=4*((a>>2)&1)
        uint8_t* dst = (LAYER ? r1 : r0)
                     + rbyte(slotC, bg, a >> 3, 16 * (a & 3) + 4 * qq + cc)
                     + 8 * ((a >> 2) & 1);
        asm volatile("global_store_dwordx2 %0, %1, off sc0 sc1\n\t"
                     "global_store_dwordx2 %0, %2, off offset:1024 sc0 sc1"
                     :: "v"(dst), "v"(hi2), "v"(lo2) : "memory");
        if (LAYER && t == T_ - 1) {
          float4v* hp = (float4v*)(h1f + (size_t)(bg * 16 + 4 * qq + cc) * H_ + 4 * a);
          asm volatile("global_store_dwordx4 %0, %1, off sc0 sc1"
                       :: "v"(hp), "v"(hf) : "memory");
        }
      }
    }
    if constexpr (FULL) {
      // per-wave drain + flag (kh0), then end-of-step barrier: own-block
      // consumers are ordered by the barrier, so nobody polls own words.
      if (kh == 0) {
        asm volatile("s_waitcnt vmcnt(0)" ::: "memory");
        if (lane == 0)
          __hip_atomic_store(&myprog[bg * 128 + a], (uint32_t)(t + 1),
                             __ATOMIC_RELAXED, __HIP_MEMORY_SCOPE_AGENT);
      }
      __syncthreads();
    } else {
      asm volatile("s_waitcnt vmcnt(0)" ::: "memory");
      __syncthreads();
      if (tid == 0)
        __hip_atomic_store(&myprog[a], (uint32_t)(t + 1),
                           __ATOMIC_RELAXED, __HIP_MEMORY_SCOPE_AGENT);
    }
  }
}

template <bool FULL>
__global__ __launch_bounds__(NTHR_, 2) void lstm_persist(
    const float* __restrict__ x,
    const float* __restrict__ Wx0, const float* __restrict__ bx0, const float* __restrict__ Wh0,
    const float* __restrict__ Wx1, const float* __restrict__ bx1, const float* __restrict__ Wh1,
    uint32_t* prog0, uint32_t* prog1,
    uint8_t* ring0, uint8_t* ring1,
    float* h1f)
{
  __shared__ unsigned short Wsh[16384];  // 32 KB: W-hi frags
  __shared__ float red[1024];            // 4 KB: split-K reduction
  if (blockIdx.x < 128)
    run_layer<0, FULL>(blockIdx.x, x, Wx0, bx0, Wh0, prog0, prog1, ring0, ring1, h1f, Wsh, red);
  else
    run_layer<1, FULL>(blockIdx.x - 128, x, Wx1, bx1, Wh1, prog0, prog1, ring0, ring1, h1f, Wsh, red);
}

__global__ void fc_out(const float* __restrict__ h1f, const float* __restrict__ Wfc,
                       const float* __restrict__ bfc, float* __restrict__ out)
{
  int tid = threadIdx.x;
  int b = tid >> 3, p = tid & 7;
  const float* hp = h1f + (size_t)b * H_ + p * 64;
  const float* wp = Wfc + p * 64;
  float4v hv[16];
  #pragma unroll
  for (int q = 0; q < 16; ++q)
    asm volatile("global_load_dwordx4 %0, %1, off sc0 sc1"
                 : "=&v"(hv[q]) : "v"(hp + 4 * q) : "memory");
  asm volatile("s_waitcnt vmcnt(0)" ::: "memory");
  float s = 0.f;
  #pragma unroll
  for (int q = 0; q < 16; ++q) {
    float4v wv = *(const float4v*)(wp + 4 * q);
    s += hv[q][0] * wv[0] + hv[q][1] * wv[1] + hv[q][2] * wv[2] + hv[q][3] * wv[3];
  }
  s += __shfl_xor(s, 1);
  s += __shfl_xor(s, 2);
  s += __shfl_xor(s, 4);
  if (p == 0) out[b] = s + bfc[0];
}

extern "C" void kernel_launch(void* const* d_in, const int* in_sizes, int n_in,
                              void* d_out, int out_size, void* d_ws, size_t ws_size,
                              hipStream_t stream)
{
  const float* x   = (const float*)d_in[0];
  const float* Wx0 = (const float*)d_in[1];
  const float* bx0 = (const float*)d_in[2];
  const float* Wh0 = (const float*)d_in[3];
  const float* Wx1 = (const float*)d_in[4];
  const float* bx1 = (const float*)d_in[5];
  const float* Wh1 = (const float*)d_in[6];
  const float* Wfc = (const float*)d_in[7];
  const float* bfc = (const float*)d_in[8];

  uint8_t* ws = (uint8_t*)d_ws;
  const size_t RINGB_FULL = (size_t)(T_ + 1) * SLOT_B;   // 65.7 MB per ring
  const size_t RINGB_CYC  = (size_t)D_ * SLOT_B;         // 1 MB per ring
  const size_t NEED_FULL  = 4096 + 2 * RINGB_FULL + (size_t)B_ * H_ * 4;

  // flags: prog[layer][bg*128+a] -> 2 x 512 u32 = 4 KB
  uint32_t* prog0 = (uint32_t*)ws;
  uint32_t* prog1 = (uint32_t*)(ws + 2048);

  if (ws_size >= NEED_FULL) {
    uint8_t* ring0 = ws + 4096;
    uint8_t* ring1 = ws + 4096 + RINGB_FULL;
    float* h1f = (float*)(ws + 4096 + 2 * RINGB_FULL);
    (void)hipMemsetAsync(ws, 0, 4096 + SLOT_B, stream);   // flags + ring0 slot0
    (void)hipMemsetAsync(ring1, 0, SLOT_B, stream);       // ring1 slot0
    hipLaunchKernelGGL(lstm_persist<true>, dim3(256), dim3(NTHR_), 0, stream,
                       x, Wx0, bx0, Wh0, Wx1, bx1, Wh1,
                       prog0, prog1, ring0, ring1, h1f);
    hipLaunchKernelGGL(fc_out, dim3(1), dim3(512), 0, stream,
                       h1f, Wfc, bfc, (float*)d_out);
  } else {
    uint8_t* ring0 = ws + 4096;
    uint8_t* ring1 = ws + 4096 + RINGB_CYC;
    float* h1f = (float*)(ws + 4096 + 2 * RINGB_CYC);
    (void)hipMemsetAsync(ws, 0, 4096 + 2 * RINGB_CYC, stream);
    hipLaunchKernelGGL(lstm_persist<false>, dim3(256), dim3(NTHR_), 0, stream,
                       x, Wx0, bx0, Wh0, Wx1, bx1, Wh1,
                       prog0, prog1, ring0, ring1, h1f);
    hipLaunchKernelGGL(fc_out, dim3(1), dim3(512), 0, stream,
                       h1f, Wfc, bfc, (float*)d_out);
  }
}